// Round 1
// baseline (319.619 us; speedup 1.0000x reference)
//
#include <hip/hip_runtime.h>
#include <math.h>

// Problem constants (match reference)
#define BATCH 8192
#define DIM   1024
#define GRP   8
constexpr float EPS = 1e-12f;
constexpr float INV_N = 1.0f / (float(BATCH) * float(DIM)); // 1 / 8388608

// ---------------------------------------------------------------------------
// Kernel 1: global sum of xf -> ws[0] (for the scalar mean)
// grid-stride float4 loads, wave shuffle reduce, one atomicAdd per block.
// ---------------------------------------------------------------------------
__global__ void sum_all_kernel(const float* __restrict__ xf,
                               float* __restrict__ ws) {
    const int tid    = blockIdx.x * blockDim.x + threadIdx.x;
    const int stride = gridDim.x * blockDim.x;
    const float4* x4 = reinterpret_cast<const float4*>(xf);
    const int n4 = (BATCH * DIM) / 4;

    float s = 0.0f;
    for (int i = tid; i < n4; i += stride) {
        float4 v = x4[i];
        s += (v.x + v.y) + (v.z + v.w);
    }
    // wave-64 butterfly
    #pragma unroll
    for (int off = 32; off > 0; off >>= 1)
        s += __shfl_down(s, off, 64);

    __shared__ float sm[4];                 // 256 threads = 4 waves
    const int lane = threadIdx.x & 63;
    const int wave = threadIdx.x >> 6;
    if (lane == 0) sm[wave] = s;
    __syncthreads();
    if (threadIdx.x == 0) {
        atomicAdd(ws, (sm[0] + sm[1]) + (sm[2] + sm[3]));
    }
}

// ---------------------------------------------------------------------------
// Kernel 2: per-row relu(x-mean), L2 normalize, scale by sigmoid(wp),
// write G=8 tiled copies. One 256-thread block per row; float4 everywhere.
// ---------------------------------------------------------------------------
__global__ __launch_bounds__(256)
void norm_tile_kernel(const float* __restrict__ xf,
                      const float* __restrict__ wp,
                      const float* __restrict__ ws,
                      float* __restrict__ out) {
    const int row = blockIdx.x;
    const int tid = threadIdx.x;          // 0..255, covers D=1024 as float4

    const float mean = ws[0] * INV_N;

    const float4* xr = reinterpret_cast<const float4*>(xf + (size_t)row * DIM);
    float4 v = xr[tid];
    v.x = fmaxf(v.x - mean, 0.0f);
    v.y = fmaxf(v.y - mean, 0.0f);
    v.z = fmaxf(v.z - mean, 0.0f);
    v.w = fmaxf(v.w - mean, 0.0f);

    float s = v.x * v.x + v.y * v.y + v.z * v.z + v.w * v.w;
    #pragma unroll
    for (int off = 32; off > 0; off >>= 1)
        s += __shfl_down(s, off, 64);

    __shared__ float sm[4];
    __shared__ float s_total;
    const int lane = tid & 63;
    const int wave = tid >> 6;
    if (lane == 0) sm[wave] = s;
    __syncthreads();
    if (tid == 0) s_total = (sm[0] + sm[1]) + (sm[2] + sm[3]);
    __syncthreads();

    const float norm  = fmaxf(sqrtf(s_total), EPS);
    const float sig   = 1.0f / (1.0f + expf(-wp[0]));
    const float scale = sig / norm;

    float4 o;
    o.x = v.x * scale;
    o.y = v.y * scale;
    o.z = v.z * scale;
    o.w = v.w * scale;

    float4* orow = reinterpret_cast<float4*>(out + (size_t)row * (GRP * DIM));
    #pragma unroll
    for (int g = 0; g < GRP; ++g)
        orow[g * (DIM / 4) + tid] = o;    // coalesced 1 KiB/wave stores
}

// ---------------------------------------------------------------------------
extern "C" void kernel_launch(void* const* d_in, const int* in_sizes, int n_in,
                              void* d_out, int out_size, void* d_ws, size_t ws_size,
                              hipStream_t stream) {
    const float* xf = (const float*)d_in[0];   // [8192,1024] fp32
    const float* wp = (const float*)d_in[1];   // [1] fp32
    // d_in[2] is W_tile — structured kron(ones(1,8), eye(1024)); not needed.
    float* out = (float*)d_out;                // [8192, 8192] fp32
    float* ws  = (float*)d_ws;

    // ws[0] holds the global sum; harness poisons ws, so zero it first.
    hipMemsetAsync(ws, 0, sizeof(float), stream);

    sum_all_kernel<<<1024, 256, 0, stream>>>(xf, ws);
    norm_tile_kernel<<<BATCH, 256, 0, stream>>>(xf, wp, ws, out);
}

// Round 3
// 301.843 us; speedup vs baseline: 1.0589x; 1.0589x over previous
//
#include <hip/hip_runtime.h>
#include <math.h>

// Problem constants (match reference)
#define BATCH 8192
#define DIM   1024
#define GRP   8
#define NPART 256                         // number of partial sums in ws
constexpr float EPS   = 1e-12f;
constexpr float INV_N = 1.0f / (float(BATCH) * float(DIM)); // 1 / 8388608

typedef float floatx4 __attribute__((ext_vector_type(4)));  // native vec for nt-store

// ---------------------------------------------------------------------------
// Kernel A: partial sums of xf -> ws[0..255]. 256 blocks x 1024 threads,
// each thread sums 8 float4s (fully unrolled), block reduce, one store.
// All 256 slots are overwritten, so no zero-init of ws is needed.
// ---------------------------------------------------------------------------
__global__ __launch_bounds__(1024)
void partial_sum_kernel(const float* __restrict__ xf,
                        float* __restrict__ ws) {
    const int tid = threadIdx.x;
    const int gid = blockIdx.x * 1024 + tid;           // 0 .. 262143
    const float4* x4 = reinterpret_cast<const float4*>(xf);
    // total float4 = 2097152 ; stride between a thread's loads = 262144
    float s = 0.0f;
    #pragma unroll
    for (int i = 0; i < 8; ++i) {
        float4 v = x4[gid + i * 262144];
        s += (v.x + v.y) + (v.z + v.w);
    }
    #pragma unroll
    for (int off = 32; off > 0; off >>= 1)
        s += __shfl_down(s, off, 64);

    __shared__ float sm[16];                           // 1024 threads = 16 waves
    const int lane = tid & 63;
    const int wave = tid >> 6;
    if (lane == 0) sm[wave] = s;
    __syncthreads();
    if (tid == 0) {
        float t = 0.0f;
        #pragma unroll
        for (int w = 0; w < 16; ++w) t += sm[w];
        ws[blockIdx.x] = t;
    }
}

// ---------------------------------------------------------------------------
// Kernel B: per-row relu(x-mean), L2 normalize, scale by sigmoid(wp),
// write G=8 tiled copies with nontemporal float4 stores.
// One 256-thread block per row. Reduces the 256 partials itself (L2-hit).
// ---------------------------------------------------------------------------
__global__ __launch_bounds__(256)
void norm_tile_kernel(const float* __restrict__ xf,
                      const float* __restrict__ wp,
                      const float* __restrict__ ws,
                      float* __restrict__ out) {
    const int row = blockIdx.x;
    const int tid = threadIdx.x;                       // 0..255

    // Issue the row load early so it overlaps the partial-sum reduction.
    const float4* xr = reinterpret_cast<const float4*>(xf + (size_t)row * DIM);
    float4 v = xr[tid];

    // Reduce the 256 partial sums -> global mean.
    float p = ws[tid];
    #pragma unroll
    for (int off = 32; off > 0; off >>= 1)
        p += __shfl_down(p, off, 64);

    __shared__ float sm[4];
    __shared__ float red[2];
    const int lane = tid & 63;
    const int wave = tid >> 6;
    if (lane == 0) sm[wave] = p;
    __syncthreads();
    if (tid == 0) red[0] = (sm[0] + sm[1]) + (sm[2] + sm[3]);
    __syncthreads();
    const float mean = red[0] * INV_N;

    // ReLU(x - mean) and row sum of squares.
    v.x = fmaxf(v.x - mean, 0.0f);
    v.y = fmaxf(v.y - mean, 0.0f);
    v.z = fmaxf(v.z - mean, 0.0f);
    v.w = fmaxf(v.w - mean, 0.0f);

    float s = v.x * v.x + v.y * v.y + v.z * v.z + v.w * v.w;
    #pragma unroll
    for (int off = 32; off > 0; off >>= 1)
        s += __shfl_down(s, off, 64);
    if (lane == 0) sm[wave] = s;                       // safe: after barrier above
    __syncthreads();
    if (tid == 0) red[1] = (sm[0] + sm[1]) + (sm[2] + sm[3]);
    __syncthreads();

    const float norm  = fmaxf(sqrtf(red[1]), EPS);
    const float sig   = 1.0f / (1.0f + expf(-wp[0]));
    const float scale = sig / norm;

    floatx4 o;
    o.x = v.x * scale;
    o.y = v.y * scale;
    o.z = v.z * scale;
    o.w = v.w * scale;

    // 8 tiled copies, nontemporal streaming stores (no reuse of out).
    floatx4* orow = reinterpret_cast<floatx4*>(out + (size_t)row * (GRP * DIM));
    #pragma unroll
    for (int g = 0; g < GRP; ++g)
        __builtin_nontemporal_store(o, &orow[g * (DIM / 4) + tid]);
}

// ---------------------------------------------------------------------------
extern "C" void kernel_launch(void* const* d_in, const int* in_sizes, int n_in,
                              void* d_out, int out_size, void* d_ws, size_t ws_size,
                              hipStream_t stream) {
    const float* xf = (const float*)d_in[0];   // [8192,1024] fp32
    const float* wp = (const float*)d_in[1];   // [1] fp32
    // d_in[2] is W_tile = kron(ones(1,8), eye(1024)) -> output is 8 tiled
    // copies of the normalized row; no GEMM needed.
    float* out = (float*)d_out;                // [8192, 8192] fp32
    float* ws  = (float*)d_ws;                 // ws[0..255] partial sums

    partial_sum_kernel<<<NPART, 1024, 0, stream>>>(xf, ws);
    norm_tile_kernel<<<BATCH, 256, 0, stream>>>(xf, wp, ws, out);
}